// Round 6
// baseline (11.778 us; speedup 1.0000x reference)
//
#include <hip/hip_runtime.h>

#define BATCH 2048
#define UNITS 512
#define DIM   64

typedef __attribute__((ext_vector_type(8))) short short8v;   // 8 bf16 (4 VGPR)
typedef __attribute__((ext_vector_type(4))) float float4v;   // MFMA C/D

// f32 -> bf16 round-to-nearest-even (finite inputs)
__device__ __forceinline__ unsigned short f2bf(float f) {
  union { float f; unsigned u; } v; v.f = f;
  return (unsigned short)((v.u + 0x7FFFu + ((v.u >> 16) & 1u)) >> 16);
}

__device__ __forceinline__ short8v pack8(const float* s) {
  union { unsigned short u16[8]; short8v v; } p;
  #pragma unroll
  for (int j = 0; j < 8; ++j) p.u16[j] = f2bf(s[j]);
  return p.v;
}

// 4 waves per block, each owning a 32b x 16u quadrant of a 64b x 32u tile.
// No LDS, no barriers: inter-wave reuse of x/q halves happens through L1.
extern "C" __global__ void __launch_bounds__(256, 2)
sausage_v6(const float* __restrict__ x, const float* __restrict__ q1,
           const float* __restrict__ q2, const float* __restrict__ r,
           float* __restrict__ out)
{
  const int tid  = threadIdx.x;
  const int lane = tid & 63;
  const int wid  = tid >> 6;           // 0..3
  const int l15  = lane & 15;          // MFMA row/col within 16
  const int lk   = lane >> 4;          // k-group 0..3
  const int b0   = blockIdx.x * 64 + (wid >> 1) * 32;   // wave's batch base
  const int u0   = blockIdx.y * 32 + (wid & 1) * 16;    // wave's unit base

  // ---------------- all global loads issued up front (L2/L1-resident) -------
  float q1f[16], q2f[16], xf[2][16];
  {
    const float* q1r = q1 + (size_t)(u0 + l15) * DIM + lk * 8;
    const float* q2r = q2 + (size_t)(u0 + l15) * DIM + lk * 8;
    #pragma unroll
    for (int ks = 0; ks < 2; ++ks) {
      *(float4*)&q1f[8*ks + 0] = *(const float4*)(q1r + ks * 32);
      *(float4*)&q1f[8*ks + 4] = *(const float4*)(q1r + ks * 32 + 4);
      *(float4*)&q2f[8*ks + 0] = *(const float4*)(q2r + ks * 32);
      *(float4*)&q2f[8*ks + 4] = *(const float4*)(q2r + ks * 32 + 4);
    }
    #pragma unroll
    for (int mt = 0; mt < 2; ++mt) {
      const float* xr = x + (size_t)(b0 + mt * 16 + l15) * DIM + lk * 8;
      #pragma unroll
      for (int ks = 0; ks < 2; ++ks) {
        *(float4*)&xf[mt][8*ks + 0] = *(const float4*)(xr + ks * 32);
        *(float4*)&xf[mt][8*ks + 4] = *(const float4*)(xr + ks * 32 + 4);
      }
    }
  }
  const float rv = r[u0 + l15];

  // ---------------- per-u scalars from this lane's fp32 k-slice -------------
  float nn = 0.f, w = 0.f, q2n = 0.f;
  #pragma unroll
  for (int j = 0; j < 16; ++j) {
    const float d = q2f[j] - q1f[j];
    nn  = fmaf(d, d, nn);
    w   = fmaf(q2f[j], d, w);
    q2n = fmaf(q2f[j], q2f[j], q2n);
  }
  float xnp0 = 0.f, xnp1 = 0.f;
  #pragma unroll
  for (int j = 0; j < 16; ++j) {
    xnp0 = fmaf(xf[0][j], xf[0][j], xnp0);
    xnp1 = fmaf(xf[1][j], xf[1][j], xnp1);
  }
  // reduce across the 4 lk-groups (lanes sharing l15): xor 16, then xor 32
  nn   += __shfl_xor(nn, 16);   nn   += __shfl_xor(nn, 32);
  w    += __shfl_xor(w, 16);    w    += __shfl_xor(w, 32);
  q2n  += __shfl_xor(q2n, 16);  q2n  += __shfl_xor(q2n, 32);
  xnp0 += __shfl_xor(xnp0, 16); xnp0 += __shfl_xor(xnp0, 32);
  xnp1 += __shfl_xor(xnp1, 16); xnp1 += __shfl_xor(xnp1, 32);

  const float t_   = w - nn;             // q1.q12
  const float qn_  = sqrtf(nn);          // ||q12||
  const float inv_ = 1.0f / (64.0f * rv * rv);

  // ---------------- convert to bf16 fragments, 8 MFMAs ----------------------
  short8v b1_frag[2], b2_frag[2], a_frag[2][2];
  #pragma unroll
  for (int ks = 0; ks < 2; ++ks) {
    b1_frag[ks] = pack8(&q1f[8 * ks]);
    b2_frag[ks] = pack8(&q2f[8 * ks]);
    a_frag[0][ks] = pack8(&xf[0][8 * ks]);
    a_frag[1][ks] = pack8(&xf[1][8 * ks]);
  }
  float4v acc1[2], acc2[2];
  #pragma unroll
  for (int mt = 0; mt < 2; ++mt) {
    acc1[mt] = (float4v){0.f, 0.f, 0.f, 0.f};
    acc2[mt] = (float4v){0.f, 0.f, 0.f, 0.f};
    #pragma unroll
    for (int ks = 0; ks < 2; ++ks) {
      acc1[mt] = __builtin_amdgcn_mfma_f32_16x16x32_bf16(a_frag[mt][ks], b1_frag[ks], acc1[mt], 0, 0, 0);
      acc2[mt] = __builtin_amdgcn_mfma_f32_16x16x32_bf16(a_frag[mt][ks], b2_frag[ks], acc2[mt], 0, 0, 0);
    }
  }

  // ---------------- redistribute ||x||^2 to C/D row owners ------------------
  float xnv[2][4];
  #pragma unroll
  for (int j = 0; j < 4; ++j) {
    xnv[0][j] = __shfl(xnp0, lk * 4 + j);
    xnv[1][j] = __shfl(xnp1, lk * 4 + j);
  }

  // ---------------- epilogue: l-select + exp + direct stores ----------------
  #pragma unroll
  for (int mt = 0; mt < 2; ++mt) {
    #pragma unroll
    for (int j = 0; j < 4; ++j) {
      const float d1 = acc1[mt][j];
      const float d2 = acc2[mt][j];
      const float a  = d2 - d1;                 // x.q12
      const float s  = a - t_;                  // (x-q1).q12
      const float l  = (s < 0.0f) ? 1.0f : ((s < qn_) ? s : 0.0f);
      const float dsq = fmaf(-2.0f, d2, xnv[mt][j]) + q2n
                      + 2.0f * l * (a - w) + l * l * nn;
      const int row = b0 + mt * 16 + lk * 4 + j;   // C/D: row=(lane>>4)*4+reg
      out[(size_t)row * UNITS + u0 + l15] = __expf(-dsq * inv_);
    }
  }
}

extern "C" void kernel_launch(void* const* d_in, const int* in_sizes, int n_in,
                              void* d_out, int out_size, void* d_ws, size_t ws_size,
                              hipStream_t stream) {
  const float* x  = (const float*)d_in[0];
  const float* q1 = (const float*)d_in[1];
  const float* q2 = (const float*)d_in[2];
  const float* r  = (const float*)d_in[3];
  float* out = (float*)d_out;
  (void)d_ws; (void)ws_size;
  dim3 grid(BATCH / 64, UNITS / 32);   // (32, 16) = 512 blocks, 2/CU, 2 waves/SIMD
  sausage_v6<<<grid, 256, 0, stream>>>(x, q1, q2, r, out);
}

// Round 7
// 11.131 us; speedup vs baseline: 1.0581x; 1.0581x over previous
//
#include <hip/hip_runtime.h>

#define BATCH 2048
#define UNITS 512
#define DIM   64

typedef __attribute__((ext_vector_type(8))) short short8v;   // 8 bf16 (4 VGPR)
typedef __attribute__((ext_vector_type(4))) float float4v;   // MFMA C/D

// f32 -> bf16 round-to-nearest-even (finite inputs)
__device__ __forceinline__ unsigned short f2bf(float f) {
  union { float f; unsigned u; } v; v.f = f;
  return (unsigned short)((v.u + 0x7FFFu + ((v.u >> 16) & 1u)) >> 16);
}

__device__ __forceinline__ short8v pack8(const float* s) {
  union { unsigned short u16[8]; short8v v; } p;
  #pragma unroll
  for (int j = 0; j < 8; ++j) p.u16[j] = f2bf(s[j]);
  return p.v;
}

// One wave per block, 32b x 16u tile; no LDS, no barriers.
// Grid 2048 single-wave blocks = 8 waves/CU = 2 waves/SIMD.
extern "C" __global__ void __launch_bounds__(64, 2)
sausage_v7(const float* __restrict__ x, const float* __restrict__ q1,
           const float* __restrict__ q2, const float* __restrict__ r,
           float* __restrict__ out)
{
  const int lane = threadIdx.x;        // 0..63
  const int l15  = lane & 15;          // MFMA row/col within 16
  const int lk   = lane >> 4;          // k-group 0..3
  const int b0   = blockIdx.x * 32;
  const int u0   = blockIdx.y * 16;

  // ---------------- all global loads issued up front (L2-resident) ----------
  float q1f[16], q2f[16], xf[2][16];
  {
    const float* q1r = q1 + (size_t)(u0 + l15) * DIM + lk * 8;
    const float* q2r = q2 + (size_t)(u0 + l15) * DIM + lk * 8;
    #pragma unroll
    for (int ks = 0; ks < 2; ++ks) {
      *(float4*)&q1f[8*ks + 0] = *(const float4*)(q1r + ks * 32);
      *(float4*)&q1f[8*ks + 4] = *(const float4*)(q1r + ks * 32 + 4);
      *(float4*)&q2f[8*ks + 0] = *(const float4*)(q2r + ks * 32);
      *(float4*)&q2f[8*ks + 4] = *(const float4*)(q2r + ks * 32 + 4);
    }
    #pragma unroll
    for (int mt = 0; mt < 2; ++mt) {
      const float* xr = x + (size_t)(b0 + mt * 16 + l15) * DIM + lk * 8;
      #pragma unroll
      for (int ks = 0; ks < 2; ++ks) {
        *(float4*)&xf[mt][8*ks + 0] = *(const float4*)(xr + ks * 32);
        *(float4*)&xf[mt][8*ks + 4] = *(const float4*)(xr + ks * 32 + 4);
      }
    }
  }
  const float rv = r[u0 + l15];

  // ---------------- per-u scalars from this lane's fp32 k-slice -------------
  // lane's 16 k-values across lk-groups tile k=0..63 exactly
  float nn = 0.f, w = 0.f, q2n = 0.f;
  #pragma unroll
  for (int j = 0; j < 16; ++j) {
    const float d = q2f[j] - q1f[j];
    nn  = fmaf(d, d, nn);
    w   = fmaf(q2f[j], d, w);
    q2n = fmaf(q2f[j], q2f[j], q2n);
  }
  float xnp0 = 0.f, xnp1 = 0.f;
  #pragma unroll
  for (int j = 0; j < 16; ++j) {
    xnp0 = fmaf(xf[0][j], xf[0][j], xnp0);
    xnp1 = fmaf(xf[1][j], xf[1][j], xnp1);
  }
  // reduce across the 4 lk-groups (lanes sharing l15): xor 16, then xor 32
  nn   += __shfl_xor(nn, 16);   nn   += __shfl_xor(nn, 32);
  w    += __shfl_xor(w, 16);    w    += __shfl_xor(w, 32);
  q2n  += __shfl_xor(q2n, 16);  q2n  += __shfl_xor(q2n, 32);
  xnp0 += __shfl_xor(xnp0, 16); xnp0 += __shfl_xor(xnp0, 32);
  xnp1 += __shfl_xor(xnp1, 16); xnp1 += __shfl_xor(xnp1, 32);

  const float t_   = w - nn;             // q1.q12
  const float qn_  = sqrtf(nn);          // ||q12||
  const float inv_ = 1.0f / (64.0f * rv * rv);

  // ---------------- convert to bf16 fragments, 8 MFMAs ----------------------
  short8v b1_frag[2], b2_frag[2], a_frag[2][2];
  #pragma unroll
  for (int ks = 0; ks < 2; ++ks) {
    b1_frag[ks] = pack8(&q1f[8 * ks]);
    b2_frag[ks] = pack8(&q2f[8 * ks]);
    a_frag[0][ks] = pack8(&xf[0][8 * ks]);
    a_frag[1][ks] = pack8(&xf[1][8 * ks]);
  }
  float4v acc1[2], acc2[2];
  #pragma unroll
  for (int mt = 0; mt < 2; ++mt) {
    acc1[mt] = (float4v){0.f, 0.f, 0.f, 0.f};
    acc2[mt] = (float4v){0.f, 0.f, 0.f, 0.f};
    #pragma unroll
    for (int ks = 0; ks < 2; ++ks) {
      acc1[mt] = __builtin_amdgcn_mfma_f32_16x16x32_bf16(a_frag[mt][ks], b1_frag[ks], acc1[mt], 0, 0, 0);
      acc2[mt] = __builtin_amdgcn_mfma_f32_16x16x32_bf16(a_frag[mt][ks], b2_frag[ks], acc2[mt], 0, 0, 0);
    }
  }

  // ---------------- redistribute ||x||^2 to C/D row owners ------------------
  // xnp{mt} (post-reduce) holds row mt*16+l15; epilogue lane needs rows lk*4+j
  float xnv[2][4];
  #pragma unroll
  for (int j = 0; j < 4; ++j) {
    xnv[0][j] = __shfl(xnp0, lk * 4 + j);
    xnv[1][j] = __shfl(xnp1, lk * 4 + j);
  }

  // ---------------- epilogue: l-select + exp + direct stores ----------------
  #pragma unroll
  for (int mt = 0; mt < 2; ++mt) {
    #pragma unroll
    for (int j = 0; j < 4; ++j) {
      const float d1 = acc1[mt][j];
      const float d2 = acc2[mt][j];
      const float a  = d2 - d1;                 // x.q12
      const float s  = a - t_;                  // (x-q1).q12
      const float l  = (s < 0.0f) ? 1.0f : ((s < qn_) ? s : 0.0f);
      const float dsq = fmaf(-2.0f, d2, xnv[mt][j]) + q2n
                      + 2.0f * l * (a - w) + l * l * nn;
      const int row = b0 + mt * 16 + lk * 4 + j;   // C/D: row=(lane>>4)*4+reg
      out[(size_t)row * UNITS + u0 + l15] = __expf(-dsq * inv_);
    }
  }
}

extern "C" void kernel_launch(void* const* d_in, const int* in_sizes, int n_in,
                              void* d_out, int out_size, void* d_ws, size_t ws_size,
                              hipStream_t stream) {
  const float* x  = (const float*)d_in[0];
  const float* q1 = (const float*)d_in[1];
  const float* q2 = (const float*)d_in[2];
  const float* r  = (const float*)d_in[3];
  float* out = (float*)d_out;
  (void)d_ws; (void)ws_size;
  dim3 grid(BATCH / 32, UNITS / 16);   // (64, 32) = 2048 single-wave blocks
  sausage_v7<<<grid, 64, 0, stream>>>(x, q1, q2, r, out);
}